// Round 11
// baseline (119.145 us; speedup 1.0000x reference)
//
#include <hip/hip_runtime.h>
#include <hip/hip_bf16.h>
#include <math.h>

// S5 SSM layer. B_SZ=16, L=1024, H=256, P=256.
// 2 dispatches:
//   k_g1scan   : M=128 GEMM1 (A: u->bf16 VALU-staged; B: coef*B~ built on the fly,
//                amortized over 128 rows) -> LDS X (2 passes) -> 4-chunk scan
//                -> XS + CEND.  Also builds W2T + PW (distributed, used by k2).
//   k_gemm2fix : parallel-prefix carry prologue + GEMM2 fixup-in-staging + D*u
#define BB     16
#define LSEQ   1024
#define HH     256
#define PP     256
#define MROWS  (BB*LSEQ)     // 16384
#define LC     32
#define NC     (LSEQ/LC)     // 32
#define NCHUNK (BB*NC)       // 512

// workspace byte offsets
#define OFF_W2T  262144u     // [256][512] bf16: row h, k=2p -> 2*C_re, 2p+1 -> -2*C_im
#define OFF_PW   524288u     // [33][256] float2: lambda_bar^t
#define OFF_CEND 655360u     // [512][256] float2 chunk-end local states
#define OFF_XS   2752512u    // [16384][512] bf16 x_local (col 2p=re, 2p+1=im)
// total ~19.5 MB

typedef __attribute__((ext_vector_type(8))) short short8;
typedef __attribute__((ext_vector_type(4))) float floatx4;

__device__ __forceinline__ float bf2f(unsigned hs) {
    union { unsigned u; float f; } v; v.u = hs << 16; return v.f;
}
__device__ __forceinline__ unsigned short f2bs(float f) {
    __hip_bfloat16 h = __float2bfloat16(f);
    union { __hip_bfloat16 h; unsigned short s; } v; v.h = h; return v.s;
}
__device__ __forceinline__ unsigned packbf(float r, float i) {
    return (unsigned)f2bs(r) | ((unsigned)f2bs(i) << 16);
}
__device__ __forceinline__ void async16(const void* g, void* l) {
    __builtin_amdgcn_global_load_lds(
        (const __attribute__((address_space(1))) unsigned*)g,
        (__attribute__((address_space(3))) unsigned*)l, 16, 0, 0);
}
__device__ __forceinline__ float2 lam_pow(float lr, float li, float dtt) {
    float m = expf(lr * dtt);
    return make_float2(m * cosf(li * dtt), m * sinf(li * dtt));
}

// ---------------- k1: GEMM1 (BM=128, BN=256, BK=64) + scan + W2T/PW build ----------
// grid 256 = 128 row-groups x 2 n-halves; 512 threads (8 waves as 2 m-halves x 4 n-slices)
#define XSTR 264    // bf16 stride of LDS X rows (132 dwords)
__global__ __launch_bounds__(512, 4) void k_g1scan(
        const float* __restrict__ u, const float* __restrict__ Lr,
        const float* __restrict__ Li, const float* __restrict__ ls,
        const float* __restrict__ Bm, const float* __restrict__ Cm,
        char* __restrict__ ws) {
    __shared__ char smem[49152];
    char* Asb = smem;                 // [2][128][32] bf16 (8 KB/panel)
    char* Bsb = smem + 16384;         // [2][256][32] bf16 (16 KB/panel)
    unsigned short* X = (unsigned short*)smem;   // [64][XSTR] (per pass)
    unsigned* X32 = (unsigned*)smem;             // stride XSTR/2
    const int tid = threadIdx.x, bx = blockIdx.x;
    const int nh = bx & 1, rg = bx >> 1;
    const int m0 = rg * 128, n0 = nh * 256;      // n0 in W1-row units
    const int wave = tid >> 6, lane = tid & 63;
    const int q = lane >> 4, rr = lane & 15;
    const int wm = wave & 1, wn = wave >> 1;

    // ---- distributed prep for k2 (independent of GEMM; runs pre-barrier) ----
    if (tid < 256) {
        float2 c = ((const float2*)Cm)[(size_t)bx * 256 + tid];
        ((unsigned*)(ws + OFF_W2T))[(size_t)bx * 256 + tid] = packbf(2.0f * c.x, -2.0f * c.y);
        if (bx < 33) {
            float lr = Lr[tid], li = Li[tid];
            ((float2*)(ws + OFF_PW))[bx * 256 + tid] =
                lam_pow(lr, li, expf(ls[tid]) * (float)bx);
        }
    }

    // ---- per-thread discretization coef for B-staging: pair pl = n0/2 + (tid>>2) ----
    const int pl = tid >> 2, hq = tid & 3;       // thread builds pair pl, 16 h's
    const int gpb = nh * 128 + pl;
    float crc, cic;
    {
        float lr = Lr[gpb], li = Li[gpb];
        float dt = expf(ls[gpb]);
        float2 lam = lam_pow(lr, li, dt);
        float den = lr * lr + li * li;
        float nr = lam.x - 1.0f, ni = lam.y;
        crc = (nr * lr + ni * li) / den;    // (lam_bar-1)/Lambda
        cic = (ni * lr - nr * li) / den;
    }
    const int arow = tid >> 2, koff = (tid & 3) * 16;   // A staging map

    floatx4 acc[4][4];
    #pragma unroll
    for (int i = 0; i < 4; ++i)
        #pragma unroll
        for (int j = 0; j < 4; ++j) acc[i][j] = (floatx4)0.0f;

    for (int k0 = 0; k0 < 256; k0 += 64) {
        __syncthreads();
        {   // A: u 128x64 fp32 -> bf16 (16 floats/thread)
            const float4* up = (const float4*)(u + (size_t)(m0 + arow) * 256 + k0 + koff);
            float4 v0 = up[0], v1 = up[1], v2 = up[2], v3 = up[3];
            char* dst = Asb + (koff >> 5) * 8192 + arow * 64 + (koff & 31) * 2;
            *(uint4*)dst = make_uint4(packbf(v0.x, v0.y), packbf(v0.z, v0.w),
                                      packbf(v1.x, v1.y), packbf(v1.z, v1.w));
            *(uint4*)(dst + 16) = make_uint4(packbf(v2.x, v2.y), packbf(v2.z, v2.w),
                                             packbf(v3.x, v3.y), packbf(v3.z, v3.w));
        }
        {   // B: W1 rows 2pl, 2pl+1 for h = k0 + hq*16 .. +15, from Bm on the fly
            const float4* bp = (const float4*)(Bm + ((size_t)gpb * 256 + k0 + hq * 16) * 2);
            int pan = hq >> 1, hh = (hq & 1) * 16;
            char* dr = Bsb + pan * 16384 + (2 * pl) * 64 + hh * 2;
            char* di = Bsb + pan * 16384 + (2 * pl + 1) * 64 + hh * 2;
            #pragma unroll
            for (int g2 = 0; g2 < 2; ++g2) {    // two groups of 8 h
                float4 b0 = bp[g2 * 4 + 0], b1 = bp[g2 * 4 + 1];
                float4 b2 = bp[g2 * 4 + 2], b3 = bp[g2 * 4 + 3];
                float re[8], im[8];
                re[0]=crc*b0.x-cic*b0.y; im[0]=crc*b0.y+cic*b0.x;
                re[1]=crc*b0.z-cic*b0.w; im[1]=crc*b0.w+cic*b0.z;
                re[2]=crc*b1.x-cic*b1.y; im[2]=crc*b1.y+cic*b1.x;
                re[3]=crc*b1.z-cic*b1.w; im[3]=crc*b1.w+cic*b1.z;
                re[4]=crc*b2.x-cic*b2.y; im[4]=crc*b2.y+cic*b2.x;
                re[5]=crc*b2.z-cic*b2.w; im[5]=crc*b2.w+cic*b2.z;
                re[6]=crc*b3.x-cic*b3.y; im[6]=crc*b3.y+cic*b3.x;
                re[7]=crc*b3.z-cic*b3.w; im[7]=crc*b3.w+cic*b3.z;
                *(uint4*)(dr + g2 * 16) = make_uint4(packbf(re[0], re[1]), packbf(re[2], re[3]),
                                                     packbf(re[4], re[5]), packbf(re[6], re[7]));
                *(uint4*)(di + g2 * 16) = make_uint4(packbf(im[0], im[1]), packbf(im[2], im[3]),
                                                     packbf(im[4], im[5]), packbf(im[6], im[7]));
            }
        }
        __syncthreads();
        #pragma unroll
        for (int ks = 0; ks < 2; ++ks) {
            short8 a[4], b[4];
            #pragma unroll
            for (int i = 0; i < 4; ++i)
                a[i] = *(const short8*)(Asb + ks * 8192 +
                                        (wm * 64 + i * 16 + rr) * 64 + q * 16);
            #pragma unroll
            for (int j = 0; j < 4; ++j)
                b[j] = *(const short8*)(Bsb + ks * 16384 +
                                        (wn * 64 + j * 16 + rr) * 64 + q * 16);
            #pragma unroll
            for (int i = 0; i < 4; ++i)
                #pragma unroll
                for (int j = 0; j < 4; ++j)
                    acc[i][j] = __builtin_amdgcn_mfma_f32_16x16x32_bf16(a[i], b[j], acc[i][j], 0, 0, 0);
        }
    }

    // ---- two passes: dump 64 rows -> scan 2 chunks each ----
    unsigned* xs32 = (unsigned*)(ws + OFF_XS);
    const int pq = tid & 127, ch = (tid >> 7) & 1;    // scan mapping (tid<256)
    const int gp = nh * 128 + pq;
    float2 lam;
    if (tid < 256) lam = lam_pow(Lr[gp], Li[gp], expf(ls[gp]));
    #pragma unroll
    for (int s = 0; s < 2; ++s) {
        __syncthreads();
        if (wm == s) {   // waves of this m-half dump their 64 rows
            #pragma unroll
            for (int i = 0; i < 4; ++i)
                #pragma unroll
                for (int j = 0; j < 4; ++j)
                    #pragma unroll
                    for (int r0 = 0; r0 < 4; ++r0)
                        X[(i * 16 + q * 4 + r0) * XSTR + wn * 64 + j * 16 + rr] =
                            f2bs(acc[i][j][r0]);
        }
        __syncthreads();
        if (tid < 256) {
            const int mrow = m0 + s * 64 + ch * 32;   // chunk base row
            float xr = 0.0f, xi = 0.0f;
            for (int j = 0; j < LC; ++j) {
                unsigned cv = X32[(ch * 32 + j) * (XSTR / 2) + pq];
                float br = bf2f(cv & 0xffffu), bi = bf2f(cv >> 16);
                float nr = fmaf(lam.x, xr, fmaf(-lam.y, xi, br));
                float ni = fmaf(lam.x, xi, fmaf(lam.y, xr, bi));
                xr = nr; xi = ni;
                xs32[(size_t)(mrow + j) * 256 + gp] = packbf(xr, xi);
            }
            ((float2*)(ws + OFF_CEND))[(size_t)(rg * 4 + s * 2 + ch) * 256 + gp] =
                make_float2(xr, xi);
        }
    }
}

// ---------------- k2: parallel-prefix carry prologue + GEMM2 fixup-in-staging ------
// out = (x_local + lam^{j+1}*carry) @ W2T^T + D*u. BM=64, BN=128, grid (2,256), BK=64.
__global__ __launch_bounds__(256, 4) void k_gemm2fix(
        const char* __restrict__ ws_c, const float* __restrict__ D,
        const float* __restrict__ u, float* __restrict__ out,
        const float* __restrict__ Lr, const float* __restrict__ Li,
        const float* __restrict__ ls) {
    __shared__ char Asb[8192];          // [2][64][32] bf16
    __shared__ char Bsb[16384];         // [2][128][32] bf16
    __shared__ float2 carrs[2][256];    // this block's 2 chunk carries
    const unsigned short* W2 = (const unsigned short*)(ws_c + OFF_W2T);
    const unsigned* xs32 = (const unsigned*)(ws_c + OFF_XS);
    const float2* pw = (const float2*)(ws_c + OFF_PW);
    const float2* cend = (const float2*)(ws_c + OFF_CEND);

    const int tid = threadIdx.x;
    const int wave = tid >> 6, lane = tid & 63;
    const int q = lane >> 4, rr = lane & 15;
    const int c4 = lane & 3, r4 = lane >> 2;
    const int wm = wave & 1, wn = wave >> 1;
    const int m0 = blockIdx.y * 64, n0 = blockIdx.x * 128;

    {   // prologue: carries for chunks cbase, cbase+1 via parallel prefix
        const int cbase = m0 >> 5;            // global chunk id (0..511)
        const int b = cbase >> 5, c = cbase & 31;
        const int p = tid;
        const float2 g = lam_pow(Lr[p], Li[p], expf(ls[p]) * (float)LC);  // lambda^LC
        float sr = 0.0f, si = 0.0f;
        float gpr = 1.0f, gpi = 0.0f;         // g^k
        for (int k = 0; k < c; ++k) {         // carry_c = sum_k g^k * e_{c-1-k}
            float2 e = cend[(size_t)(b * NC + (c - 1 - k)) * 256 + p];
            sr = fmaf(gpr, e.x, fmaf(-gpi, e.y, sr));
            si = fmaf(gpr, e.y, fmaf(gpi, e.x, si));
            float t = gpr * g.x - gpi * g.y;
            gpi = gpr * g.y + gpi * g.x; gpr = t;
        }
        carrs[0][p] = make_float2(sr, si);
        float2 e = cend[(size_t)cbase * 256 + p];
        carrs[1][p] = make_float2(fmaf(g.x, sr, fmaf(-g.y, si, e.x)),
                                  fmaf(g.x, si, fmaf(g.y, sr, e.y)));
    }

    floatx4 acc[2][4];
    #pragma unroll
    for (int i = 0; i < 2; ++i)
        #pragma unroll
        for (int j = 0; j < 4; ++j) acc[i][j] = (floatx4)0.0f;

    const int row = tid >> 2, qd = tid & 3;    // staging: 8 pairs/thread/iter
    const int grow = m0 + row;
    const int jj = (grow & (LC - 1)) + 1;
    const int half = row >> 5;

    for (int k0 = 0; k0 < 512; k0 += 64) {
        __syncthreads();   // publishes carrs on first iteration
        {
            int p0 = (k0 >> 1) + qd * 8;
            uint4 xa = *(const uint4*)(xs32 + (size_t)grow * 256 + p0);
            uint4 xb = *(const uint4*)(xs32 + (size_t)grow * 256 + p0 + 4);
            unsigned xv[8] = {xa.x, xa.y, xa.z, xa.w, xb.x, xb.y, xb.z, xb.w};
            const float2* pwp = pw + (size_t)jj * 256 + p0;
            const float2* cap = &carrs[half][p0];
            unsigned o[8];
            #pragma unroll
            for (int e = 0; e < 8; ++e) {
                float2 pwv = pwp[e];
                float2 cav = cap[e];
                float fr = pwv.x * cav.x - pwv.y * cav.y;
                float fi = pwv.x * cav.y + pwv.y * cav.x;
                o[e] = packbf(bf2f(xv[e] & 0xffffu) + fr, bf2f(xv[e] >> 16) + fi);
            }
            char* dst = Asb + (qd >> 1) * 4096 + row * 64 + (qd & 1) * 32;
            *(uint4*)dst        = make_uint4(o[0], o[1], o[2], o[3]);
            *(uint4*)(dst + 16) = make_uint4(o[4], o[5], o[6], o[7]);
        }
        #pragma unroll
        for (int t = 0; t < 4; ++t) {          // Bs: 128 rows x 2 panels
            int idx = t * 4 + wave;
            int pan = idx & 1, rowg = idx >> 1;
            int rw = rowg * 16 + r4;
            async16(W2 + (size_t)(n0 + rw) * 512 + k0 + pan * 32 + c4 * 8,
                    Bsb + pan * 8192 + rw * 64 + c4 * 16);
        }
        __syncthreads();
        #pragma unroll
        for (int ks = 0; ks < 2; ++ks) {
            short8 a[2], bfr[4];
            #pragma unroll
            for (int i = 0; i < 2; ++i)
                a[i] = *(const short8*)(Asb + ks * 4096 +
                                        (wm * 32 + i * 16 + rr) * 64 + q * 16);
            #pragma unroll
            for (int j = 0; j < 4; ++j)
                bfr[j] = *(const short8*)(Bsb + ks * 8192 +
                                          ((wn * 64 + j * 16 + rr)) * 64 + q * 16);
            #pragma unroll
            for (int i = 0; i < 2; ++i)
                #pragma unroll
                for (int j = 0; j < 4; ++j)
                    acc[i][j] = __builtin_amdgcn_mfma_f32_16x16x32_bf16(a[i], bfr[j], acc[i][j], 0, 0, 0);
        }
    }

    #pragma unroll
    for (int i = 0; i < 2; ++i) {
        int mbase = m0 + wm * 32 + i * 16 + q * 4;
        #pragma unroll
        for (int j = 0; j < 4; ++j) {
            int col = n0 + wn * 64 + j * 16 + rr;
            #pragma unroll
            for (int r0 = 0; r0 < 4; ++r0) {
                int rw = mbase + r0;
                size_t gi = (size_t)rw * 256 + col;
                out[gi] = acc[i][j][r0] + D[col] * u[gi];
            }
        }
    }
}

extern "C" void kernel_launch(void* const* d_in, const int* in_sizes, int n_in,
                              void* d_out, int out_size, void* d_ws, size_t ws_size,
                              hipStream_t stream) {
    const float* u  = (const float*)d_in[0];
    const float* Lr = (const float*)d_in[1];
    const float* Li = (const float*)d_in[2];
    const float* Bm = (const float*)d_in[3];
    const float* Cm = (const float*)d_in[4];
    const float* D  = (const float*)d_in[5];
    const float* ls = (const float*)d_in[6];
    float* out = (float*)d_out;
    char* ws = (char*)d_ws;

    k_g1scan<<<256, 512, 0, stream>>>(u, Lr, Li, ls, Bm, Cm, ws);
    k_gemm2fix<<<dim3(2, MROWS / 64), 256, 0, stream>>>(ws, D, u, out, Lr, Li, ls);
}

// Round 12
// 113.268 us; speedup vs baseline: 1.0519x; 1.0519x over previous
//
#include <hip/hip_runtime.h>
#include <hip/hip_bf16.h>
#include <math.h>

// S5 SSM layer. B_SZ=16, L=1024, H=256, P=256.
// 3 dispatches (best-measured configuration, R10 = 114.4 us):
//   k_prep     : W1T, W2T, PW (lambda-power table)
//   k_g1scan   : per-(chunk, n-half) GEMM1 (BK=64) -> LDS X -> local scan -> XS + CEND
//   k_gemm2fix : parallel-prefix carry prologue + GEMM2 with fixup-in-staging + D*u
#define BB     16
#define LSEQ   1024
#define HH     256
#define PP     256
#define MROWS  (BB*LSEQ)     // 16384
#define LC     32
#define NC     (LSEQ/LC)     // 32
#define NCHUNK (BB*NC)       // 512

// workspace byte offsets
#define OFF_W1T  0u          // [512][256] bf16: row 2p=Re(B_bar[p][.]), 2p+1=Im
#define OFF_W2T  262144u     // [256][512] bf16: row h, k=2p -> 2*C_re, 2p+1 -> -2*C_im
#define OFF_PW   524288u     // [33][256] float2: lambda_bar^t
#define OFF_CEND 655360u     // [512][256] float2 chunk-end local states
#define OFF_XS   2752512u    // [16384][512] bf16 x_local (col 2p=re, 2p+1=im)
// total ~19.5 MB

typedef __attribute__((ext_vector_type(8))) short short8;
typedef __attribute__((ext_vector_type(4))) float floatx4;

__device__ __forceinline__ float bf2f(unsigned hs) {
    union { unsigned u; float f; } v; v.u = hs << 16; return v.f;
}
__device__ __forceinline__ unsigned short f2bs(float f) {
    __hip_bfloat16 h = __float2bfloat16(f);
    union { __hip_bfloat16 h; unsigned short s; } v; v.h = h; return v.s;
}
__device__ __forceinline__ unsigned packbf(float r, float i) {
    return (unsigned)f2bs(r) | ((unsigned)f2bs(i) << 16);
}
__device__ __forceinline__ void async16(const void* g, void* l) {
    __builtin_amdgcn_global_load_lds(
        (const __attribute__((address_space(1))) unsigned*)g,
        (__attribute__((address_space(3))) unsigned*)l, 16, 0, 0);
}
__device__ __forceinline__ float2 lam_pow(float lr, float li, float dtt) {
    float m = expf(lr * dtt);
    return make_float2(m * cosf(li * dtt), m * sinf(li * dtt));
}

// ---------------- prep: W1T/PW (blocks 0..255) and W2T (256..511) ----------------
__global__ void k_prep(const float* __restrict__ Bm, const float* __restrict__ Cm,
                       const float* __restrict__ Lr, const float* __restrict__ Li,
                       const float* __restrict__ ls, char* __restrict__ ws) {
    int blk = blockIdx.x, t = threadIdx.x;
    if (blk < 256) {
        int p = blk, h = t;
        float lr = Lr[p], li = Li[p];
        float dt = expf(ls[p]);
        float2 lam = lam_pow(lr, li, dt);
        float den = lr * lr + li * li;
        float nr = lam.x - 1.0f, ni = lam.y;
        float cr = (nr * lr + ni * li) / den;       // (lam_bar-1)/Lambda
        float ci = (ni * lr - nr * li) / den;
        float br = Bm[(p * HH + h) * 2 + 0];
        float bi = Bm[(p * HH + h) * 2 + 1];
        unsigned short* w1 = (unsigned short*)(ws + OFF_W1T);
        w1[(2 * p) * 256 + h]     = f2bs(cr * br - ci * bi);
        w1[(2 * p + 1) * 256 + h] = f2bs(cr * bi + ci * br);
        if (t <= 32)   // lambda power table pw[t][p]
            ((float2*)(ws + OFF_PW))[t * 256 + p] = lam_pow(lr, li, dt * (float)t);
    } else {
        int h = blk - 256, p = t;
        float c_r = Cm[(h * PP + p) * 2 + 0];
        float c_i = Cm[(h * PP + p) * 2 + 1];
        ((unsigned*)(ws + OFF_W2T))[h * 256 + p] = packbf(2.0f * c_r, -2.0f * c_i);
    }
}

// ---------------- GEMM1 + local chunk scan; grid 1024 = 512 chunks x 2 n-halves ----
// 512 threads (8 waves, 32-col slice each). BM=32, BN=256, BK=64 two-panel.
#define XSTR2 268    // bf16 stride of LDS X rows (134 dwords; q-rows spread banks)
__global__ __launch_bounds__(512, 6) void k_g1scan(
        const float* __restrict__ u, const float* __restrict__ Lr,
        const float* __restrict__ Li, const float* __restrict__ ls,
        char* __restrict__ ws) {
    __shared__ char smem[36864];
    char* Asb = smem;                 // [2][32][32] bf16 (2 KB/panel)
    char* Bsb = smem + 4096;          // [2][256][32] bf16 (16 KB/panel)
    unsigned short* X = (unsigned short*)smem;   // [32][XSTR2] after GEMM (17 KB)
    unsigned* X32 = (unsigned*)smem;             // stride XSTR2/2
    const unsigned short* W1 = (const unsigned short*)(ws + OFF_W1T);
    const int tid = threadIdx.x, bx = blockIdx.x;
    const int nh = bx & 1, bc = bx >> 1;
    const int m0 = bc * LC, n0 = nh * 256;
    const int wave = tid >> 6, lane = tid & 63;
    const int q = lane >> 4, rr = lane & 15;
    const int c4 = lane & 3, r4 = lane >> 2;

    floatx4 acc[2][2];
    #pragma unroll
    for (int i = 0; i < 2; ++i)
        #pragma unroll
        for (int j = 0; j < 2; ++j) acc[i][j] = (floatx4)0.0f;

    const int arow = tid >> 4, acol4 = (tid & 15) * 4;   // A-stage: 1 float4/thread
    for (int k0 = 0; k0 < 256; k0 += 64) {
        __syncthreads();
        {   // A panel: u 32x64 fp32 -> bf16
            float4 v = *(const float4*)(u + (size_t)(m0 + arow) * 256 + k0 + acol4);
            *(uint2*)(Asb + (acol4 >> 5) * 2048 + arow * 64 + (acol4 & 31) * 2) =
                make_uint2(packbf(v.x, v.y), packbf(v.z, v.w));
        }
        #pragma unroll
        for (int t = 0; t < 4; ++t) {   // B: 256 rows x 2 panels via DMA
            int idx = t * 8 + wave;     // 0..31
            int pan = idx & 1, rowg = idx >> 1;
            int row = rowg * 16 + r4;
            async16(W1 + (size_t)(n0 + row) * 256 + k0 + pan * 32 + c4 * 8,
                    Bsb + pan * 16384 + row * 64 + c4 * 16);
        }
        __syncthreads();
        #pragma unroll
        for (int ks = 0; ks < 2; ++ks) {
            short8 a0 = *(const short8*)(Asb + ks * 2048 + rr * 64 + q * 16);
            short8 a1 = *(const short8*)(Asb + ks * 2048 + (16 + rr) * 64 + q * 16);
            #pragma unroll
            for (int j = 0; j < 2; ++j) {
                short8 b = *(const short8*)(Bsb + ks * 16384 +
                                            (wave * 32 + j * 16 + rr) * 64 + q * 16);
                acc[0][j] = __builtin_amdgcn_mfma_f32_16x16x32_bf16(a0, b, acc[0][j], 0, 0, 0);
                acc[1][j] = __builtin_amdgcn_mfma_f32_16x16x32_bf16(a1, b, acc[1][j], 0, 0, 0);
            }
        }
    }
    __syncthreads();
    // dump Bu tile (32 x 256) into padded LDS X
    #pragma unroll
    for (int i = 0; i < 2; ++i)
        #pragma unroll
        for (int j = 0; j < 2; ++j)
            #pragma unroll
            for (int r0 = 0; r0 < 4; ++r0)
                X[(i * 16 + q * 4 + r0) * XSTR2 + wave * 32 + j * 16 + rr] =
                    f2bs(acc[i][j][r0]);
    __syncthreads();

    // local chunk scan: 128 units (this n-half's channel pairs)
    if (tid < 128) {
        const int pq = tid;
        const int gp = nh * 128 + pq;                  // global channel pair
        const float2 lam = lam_pow(Lr[gp], Li[gp], expf(ls[gp]));
        unsigned* xs32 = (unsigned*)(ws + OFF_XS);
        float xr = 0.0f, xi = 0.0f;
        for (int j = 0; j < LC; ++j) {
            unsigned cv = X32[j * (XSTR2 / 2) + pq];
            float br = bf2f(cv & 0xffffu), bi = bf2f(cv >> 16);
            float nr = fmaf(lam.x, xr, fmaf(-lam.y, xi, br));
            float ni = fmaf(lam.x, xi, fmaf(lam.y, xr, bi));
            xr = nr; xi = ni;
            xs32[(size_t)(m0 + j) * 256 + gp] = packbf(xr, xi);
        }
        ((float2*)(ws + OFF_CEND))[(size_t)bc * 256 + gp] = make_float2(xr, xi);
    }
}

// ---------------- GEMM2: parallel-prefix carry prologue + fixup-in-staging ----------
// out = (x_local + lam^{j+1}*carry) @ W2T^T + D*u. BM=64, BN=128, grid (2,256), BK=64.
__global__ __launch_bounds__(256, 4) void k_gemm2fix(
        const char* __restrict__ ws_c, const float* __restrict__ D,
        const float* __restrict__ u, float* __restrict__ out,
        const float* __restrict__ Lr, const float* __restrict__ Li,
        const float* __restrict__ ls) {
    __shared__ char Asb[8192];          // [2][64][32] bf16
    __shared__ char Bsb[16384];         // [2][128][32] bf16
    __shared__ float2 carrs[2][256];    // this block's 2 chunk carries
    const unsigned short* W2 = (const unsigned short*)(ws_c + OFF_W2T);
    const unsigned* xs32 = (const unsigned*)(ws_c + OFF_XS);
    const float2* pw = (const float2*)(ws_c + OFF_PW);
    const float2* cend = (const float2*)(ws_c + OFF_CEND);

    const int tid = threadIdx.x;
    const int wave = tid >> 6, lane = tid & 63;
    const int q = lane >> 4, rr = lane & 15;
    const int c4 = lane & 3, r4 = lane >> 2;
    const int wm = wave & 1, wn = wave >> 1;
    const int m0 = blockIdx.y * 64, n0 = blockIdx.x * 128;

    {   // prologue: carries for chunks cbase, cbase+1 via parallel prefix
        const int cbase = m0 >> 5;            // global chunk id (0..511)
        const int b = cbase >> 5, c = cbase & 31;
        const int p = tid;
        const float2 g = lam_pow(Lr[p], Li[p], expf(ls[p]) * (float)LC);  // lambda^LC
        float sr = 0.0f, si = 0.0f;
        float gpr = 1.0f, gpi = 0.0f;         // g^k
        for (int k = 0; k < c; ++k) {         // carry_c = sum_k g^k * e_{c-1-k}
            float2 e = cend[(size_t)(b * NC + (c - 1 - k)) * 256 + p];
            sr = fmaf(gpr, e.x, fmaf(-gpi, e.y, sr));
            si = fmaf(gpr, e.y, fmaf(gpi, e.x, si));
            float t = gpr * g.x - gpi * g.y;
            gpi = gpr * g.y + gpi * g.x; gpr = t;
        }
        carrs[0][p] = make_float2(sr, si);
        float2 e = cend[(size_t)cbase * 256 + p];
        carrs[1][p] = make_float2(fmaf(g.x, sr, fmaf(-g.y, si, e.x)),
                                  fmaf(g.x, si, fmaf(g.y, sr, e.y)));
    }

    floatx4 acc[2][4];
    #pragma unroll
    for (int i = 0; i < 2; ++i)
        #pragma unroll
        for (int j = 0; j < 4; ++j) acc[i][j] = (floatx4)0.0f;

    const int row = tid >> 2, qd = tid & 3;    // staging: 8 pairs/thread/iter
    const int grow = m0 + row;
    const int jj = (grow & (LC - 1)) + 1;
    const int half = row >> 5;

    for (int k0 = 0; k0 < 512; k0 += 64) {
        __syncthreads();   // publishes carrs on first iteration
        {
            int p0 = (k0 >> 1) + qd * 8;
            uint4 xa = *(const uint4*)(xs32 + (size_t)grow * 256 + p0);
            uint4 xb = *(const uint4*)(xs32 + (size_t)grow * 256 + p0 + 4);
            unsigned xv[8] = {xa.x, xa.y, xa.z, xa.w, xb.x, xb.y, xb.z, xb.w};
            const float2* pwp = pw + (size_t)jj * 256 + p0;
            const float2* cap = &carrs[half][p0];
            unsigned o[8];
            #pragma unroll
            for (int e = 0; e < 8; ++e) {
                float2 pwv = pwp[e];
                float2 cav = cap[e];
                float fr = pwv.x * cav.x - pwv.y * cav.y;
                float fi = pwv.x * cav.y + pwv.y * cav.x;
                o[e] = packbf(bf2f(xv[e] & 0xffffu) + fr, bf2f(xv[e] >> 16) + fi);
            }
            char* dst = Asb + (qd >> 1) * 4096 + row * 64 + (qd & 1) * 32;
            *(uint4*)dst        = make_uint4(o[0], o[1], o[2], o[3]);
            *(uint4*)(dst + 16) = make_uint4(o[4], o[5], o[6], o[7]);
        }
        #pragma unroll
        for (int t = 0; t < 4; ++t) {          // Bs: 128 rows x 2 panels
            int idx = t * 4 + wave;
            int pan = idx & 1, rowg = idx >> 1;
            int rw = rowg * 16 + r4;
            async16(W2 + (size_t)(n0 + rw) * 512 + k0 + pan * 32 + c4 * 8,
                    Bsb + pan * 8192 + rw * 64 + c4 * 16);
        }
        __syncthreads();
        #pragma unroll
        for (int ks = 0; ks < 2; ++ks) {
            short8 a[2], bfr[4];
            #pragma unroll
            for (int i = 0; i < 2; ++i)
                a[i] = *(const short8*)(Asb + ks * 4096 +
                                        (wm * 32 + i * 16 + rr) * 64 + q * 16);
            #pragma unroll
            for (int j = 0; j < 4; ++j)
                bfr[j] = *(const short8*)(Bsb + ks * 8192 +
                                          ((wn * 64 + j * 16 + rr)) * 64 + q * 16);
            #pragma unroll
            for (int i = 0; i < 2; ++i)
                #pragma unroll
                for (int j = 0; j < 4; ++j)
                    acc[i][j] = __builtin_amdgcn_mfma_f32_16x16x32_bf16(a[i], bfr[j], acc[i][j], 0, 0, 0);
        }
    }

    #pragma unroll
    for (int i = 0; i < 2; ++i) {
        int mbase = m0 + wm * 32 + i * 16 + q * 4;
        #pragma unroll
        for (int j = 0; j < 4; ++j) {
            int col = n0 + wn * 64 + j * 16 + rr;
            #pragma unroll
            for (int r0 = 0; r0 < 4; ++r0) {
                int rw = mbase + r0;
                size_t gi = (size_t)rw * 256 + col;
                out[gi] = acc[i][j][r0] + D[col] * u[gi];
            }
        }
    }
}

extern "C" void kernel_launch(void* const* d_in, const int* in_sizes, int n_in,
                              void* d_out, int out_size, void* d_ws, size_t ws_size,
                              hipStream_t stream) {
    const float* u  = (const float*)d_in[0];
    const float* Lr = (const float*)d_in[1];
    const float* Li = (const float*)d_in[2];
    const float* Bm = (const float*)d_in[3];
    const float* Cm = (const float*)d_in[4];
    const float* D  = (const float*)d_in[5];
    const float* ls = (const float*)d_in[6];
    float* out = (float*)d_out;
    char* ws = (char*)d_ws;

    k_prep<<<512, 256, 0, stream>>>(Bm, Cm, Lr, Li, ls, ws);
    k_g1scan<<<1024, 512, 0, stream>>>(u, Lr, Li, ls, ws);
    k_gemm2fix<<<dim3(2, MROWS / 64), 256, 0, stream>>>(ws, D, u, out, Lr, Li, ls);
}